// Round 9
// baseline (413.945 us; speedup 1.0000x reference)
//
#include <hip/hip_runtime.h>
#include <hip/hip_bf16.h>
#include <math.h>

#define N_USERS 100000
#define N_ITEMS 50000
#define N_EDGES 2000000
#define D 64

// Segment-keyed coarse bins: fwd bin = (d>>9)*8 + (s>>14), bwd = (s>>9)*4 + (d>>14)
#define SEG_SH 14
#define FSEG 8
#define BSEG 4
#define FB2 (98 * FSEG)              // 784
#define BB2 (196 * BSEG)             // 784
#define NB2 (FB2 + BB2)              // 1568
#define CHUNK 16384
#define NCHUNK ((N_EDGES + CHUNK - 1) / CHUNK)   // 123
#define FWD_WGS 782
#define BWD_WGS 1563
#define CAPR 4096                    // refine in-LDS cell capacity (mean 2551, sd ~50)
#define CAPP 1024                    // pass2 sub-cell capacity (mean ~320)

// ---- bf16 pack/unpack helpers --------------------------------------------
__device__ __forceinline__ float blo(unsigned u) {
    union { unsigned i; float f; } c; c.i = u << 16; return c.f;
}
__device__ __forceinline__ float bhi(unsigned u) {
    union { unsigned i; float f; } c; c.i = u & 0xFFFF0000u; return c.f;
}
__device__ __forceinline__ unsigned bpack(float x, float y) {
    __hip_bfloat16 a = __float2bfloat16(x), b = __float2bfloat16(y);
    unsigned short ua = *reinterpret_cast<unsigned short*>(&a);
    unsigned short ub = *reinterpret_cast<unsigned short*>(&b);
    return (unsigned)ua | ((unsigned)ub << 16);
}

// ---------------------------------------------------------------------------
__global__ __launch_bounds__(256) void h2b_kernel(
    const float2* __restrict__ in, unsigned* __restrict__ out, int n) {
    int stride = gridDim.x * blockDim.x;
    for (int i = blockIdx.x * blockDim.x + threadIdx.x; i < n; i += stride) {
        float2 v = in[i];
        out[i] = bpack(v.x, v.y);
    }
}

// ---------------------------------------------------------------------------
__global__ __launch_bounds__(256) void hist_kernel(
    const int* __restrict__ src, const int* __restrict__ dst, int* __restrict__ gh) {
    __shared__ int h[NB2];
    for (int i = threadIdx.x; i < NB2; i += 256) h[i] = 0;
    __syncthreads();
    int stride = gridDim.x * blockDim.x;
    for (int e = blockIdx.x * blockDim.x + threadIdx.x; e < N_EDGES; e += stride) {
        int s = src[e], d = dst[e];
        atomicAdd(&h[(d >> 9) * FSEG + (s >> SEG_SH)], 1);
        atomicAdd(&h[FB2 + (s >> 9) * BSEG + (d >> SEG_SH)], 1);
    }
    __syncthreads();
    for (int i = threadIdx.x; i < NB2; i += 256) {
        int v = h[i];
        if (v) atomicAdd(&gh[i], v);
    }
}

// ---------------------------------------------------------------------------
__global__ void scan_excl(const int* __restrict__ in, int* __restrict__ out,
                          int* __restrict__ cur, int n) {
    const int T = 1024, E = 4;
    __shared__ int wsum[16];
    __shared__ int s_carry;
    if (threadIdx.x == 0) s_carry = 0;
    __syncthreads();

    int lane = threadIdx.x & 63;
    int wid  = threadIdx.x >> 6;

    for (int base = 0; base < n; base += T * E) {
        int idx0 = base + threadIdx.x * E;
        int v[E];
        int tot = 0;
#pragma unroll
        for (int e = 0; e < E; e++) {
            int i = idx0 + e;
            v[e] = (i < n) ? in[i] : 0;
            tot += v[e];
        }
        int incl = tot;
#pragma unroll
        for (int off = 1; off < 64; off <<= 1) {
            int t = __shfl_up(incl, off);
            if (lane >= off) incl += t;
        }
        if (lane == 63) wsum[wid] = incl;
        __syncthreads();
        if (wid == 0 && lane < 16) {
            int t = wsum[lane];
            int sc = t;
#pragma unroll
            for (int off = 1; off < 16; off <<= 1) {
                int u = __shfl_up(sc, off);
                if (lane >= off) sc += u;
            }
            wsum[lane] = sc - t;
        }
        __syncthreads();
        int wave_off = wsum[wid];
        int excl = s_carry + wave_off + incl - tot;
#pragma unroll
        for (int e = 0; e < E; e++) {
            int i = idx0 + e;
            if (i < n) { out[i] = excl; cur[i] = excl; }
            excl += v[e];
        }
        __syncthreads();
        if (threadIdx.x == T - 1) s_carry += wave_off + incl;
        __syncthreads();
    }
    if (threadIdx.x == 0) out[n] = s_carry;
}

// ---------------------------------------------------------------------------
// binfill: two-scan chunk-aggregated scatter over 1568 bins (runs ~21 entries).
// fwd entry: s(17b) | d_local9<<17 ; bwd entry: d(16b) | s_local9<<16.
// ---------------------------------------------------------------------------
__global__ __launch_bounds__(256) void binfill_kernel(
    const int* __restrict__ src, const int* __restrict__ dst,
    int* __restrict__ gcur, unsigned* __restrict__ stage) {
    __shared__ int cnt[NB2];
    __shared__ int gbase[NB2];
    __shared__ int lcur[NB2];
    int base = blockIdx.x * CHUNK;
    int nE = N_EDGES - base; if (nE > CHUNK) nE = CHUNK;

    for (int t = threadIdx.x; t < NB2; t += 256) { cnt[t] = 0; lcur[t] = 0; }
    __syncthreads();

    for (int k = threadIdx.x; k < nE; k += 256) {
        int s = src[base + k], d = dst[base + k];
        atomicAdd(&cnt[(d >> 9) * FSEG + (s >> SEG_SH)], 1);
        atomicAdd(&cnt[FB2 + (s >> 9) * BSEG + (d >> SEG_SH)], 1);
    }
    __syncthreads();
    for (int t = threadIdx.x; t < NB2; t += 256) {
        int cv = cnt[t];
        gbase[t] = cv ? atomicAdd(&gcur[t], cv) : 0;
    }
    __syncthreads();
    for (int k = threadIdx.x; k < nE; k += 256) {
        int s = src[base + k], d = dst[base + k];
        int bf = (d >> 9) * FSEG + (s >> SEG_SH);
        int p = atomicAdd(&lcur[bf], 1);
        stage[gbase[bf] + p] = (unsigned)s | ((unsigned)(d & 511) << 17);
        int bb = FB2 + (s >> 9) * BSEG + (d >> SEG_SH);
        int q2 = atomicAdd(&lcur[bb], 1);
        stage[gbase[bb] + q2] = (unsigned)d | ((unsigned)(s & 511) << 16);
    }
}

// ---------------------------------------------------------------------------
// refine: one 512-thread WG per cell. In-LDS counting-sort of the cell by its
// 9-bit local id (entries unchanged, reordered, written back densely) and
// per-local-id offset table itemoff[c*512 + dl]. Overflow cells flagged -1.
// ---------------------------------------------------------------------------
__global__ __launch_bounds__(512) void refine_kernel(
    unsigned* __restrict__ stage, const int* __restrict__ binoff,
    int* __restrict__ itemoff) {
    __shared__ unsigned ebuf[CAPR];
    __shared__ unsigned sbuf[CAPR];
    __shared__ int cnt[512];
    __shared__ int loc[512];
    __shared__ int lcur[512];
    __shared__ int part[8];
    int c = blockIdx.x;
    int beg = binoff[c], end = binoff[c + 1];
    int n = end - beg;
    int tid = threadIdx.x, lane = tid & 63, wv = tid >> 6;
    int sh = (c < FB2) ? 17 : 16;

    if (n > CAPR) {   // statistically unreachable; flag for pass2 fallback
        itemoff[(size_t)c * 512 + tid] = -1;
        return;
    }

    cnt[tid] = 0; lcur[tid] = 0;
    for (int k = tid; k < n; k += 512) ebuf[k] = stage[beg + k];
    __syncthreads();
    for (int k = tid; k < n; k += 512)
        atomicAdd(&cnt[(ebuf[k] >> sh) & 511], 1);
    __syncthreads();
    // exclusive scan of 512 counters
    {
        int v = cnt[tid];
        int incl = v;
#pragma unroll
        for (int off = 1; off < 64; off <<= 1) {
            int t = __shfl_up(incl, off);
            if (lane >= off) incl += t;
        }
        if (lane == 63) part[wv] = incl;
        __syncthreads();
        if (tid == 0) {
            int run = 0;
#pragma unroll
            for (int w = 0; w < 8; w++) { int t = part[w]; part[w] = run; run += t; }
        }
        __syncthreads();
        loc[tid] = incl - v + part[wv];
    }
    __syncthreads();
    for (int k = tid; k < n; k += 512) {
        unsigned e = ebuf[k];
        int dl = (e >> sh) & 511;
        int p = atomicAdd(&lcur[dl], 1);
        sbuf[loc[dl] + p] = e;
    }
    __syncthreads();
    for (int k = tid; k < n; k += 512) stage[beg + k] = sbuf[k];
    itemoff[(size_t)c * 512 + tid] = beg + loc[tid];
}

// ---------------------------------------------------------------------------
__global__ void softmax_stats_kernel(const float* __restrict__ w, float* __restrict__ stats) {
    __shared__ float red[16];
    int tid = threadIdx.x, lane = tid & 63, wid = tid >> 6;

    float m = -INFINITY;
    for (int i = tid; i < N_ITEMS; i += 1024) m = fmaxf(m, w[i]);
#pragma unroll
    for (int off = 32; off; off >>= 1) m = fmaxf(m, __shfl_xor(m, off));
    if (lane == 0) red[wid] = m;
    __syncthreads();
    if (tid == 0) {
        float t = red[0];
        for (int k = 1; k < 16; k++) t = fmaxf(t, red[k]);
        red[0] = t;
    }
    __syncthreads();
    m = red[0];
    __syncthreads();

    float s = 0.f;
    for (int i = tid; i < N_ITEMS; i += 1024) s += expf(w[i] - m);
#pragma unroll
    for (int off = 32; off; off >>= 1) s += __shfl_xor(s, off);
    if (lane == 0) red[wid] = s;
    __syncthreads();
    if (tid == 0) {
        float t = 0.f;
        for (int k = 0; k < 16; k++) t += red[k];
        stats[0] = m;
        stats[1] = t;
    }
}

// ---------------------------------------------------------------------------
// pass2 fwd: one 512-thread WG per 64 items, segment-outer, NO sort/filter:
// per segment, load 65 group bounds + copy the contiguous pre-sorted sub-cell
// into LDS, gather bf16 rows with per-item VGPR accumulators.
// ---------------------------------------------------------------------------
__global__ __launch_bounds__(512) void pass2_fwd_kernel(
    const unsigned* __restrict__ hu16, const float* __restrict__ pf,
    const float* __restrict__ edge_w, const unsigned* __restrict__ stage,
    const int* __restrict__ binoff, const int* __restrict__ itemoff,
    const float* __restrict__ stats, unsigned* __restrict__ rst16) {
    __shared__ int loc_l[65];
    __shared__ unsigned sorted[CAPP];
    int r = blockIdx.x;
    int B = r >> 3, g = r & 7;
    int tid = threadIdx.x, lane = tid & 63, wv = tid >> 6;
    int q = lane & 31, half = lane >> 5;

    float ax[8], ay[8];
    int dg[8];
#pragma unroll
    for (int j = 0; j < 8; j++) { ax[j] = 0.f; ay[j] = 0.f; dg[j] = 0; }

    for (int seg = 0; seg < FSEG; seg++) {
        int c = B * FSEG + seg;
        if (tid <= 64) {
            int dl = g * 64 + tid;
            loc_l[tid] = (dl == 512) ? binoff[c + 1] : itemoff[(size_t)c * 512 + dl];
        }
        __syncthreads();
        if (loc_l[0] >= 0) {
            int loc0 = loc_l[0];
            int n = loc_l[64] - loc0;
            if (n <= CAPP) {
                for (int k = tid; k < n; k += 512) sorted[k] = stage[loc0 + k];
                __syncthreads();
#pragma unroll
                for (int j = 0; j < 8; j++) {
                    int il = wv + 8 * j;
                    int a = loc_l[il] - loc0, b = loc_l[il + 1] - loc0;
                    dg[j] += b - a;
                    int k = a;
                    for (; k + 4 <= b; k += 4) {
                        int s0 = (int)(sorted[k + half] & 0x1FFFFu);
                        int s1 = (int)(sorted[k + 2 + half] & 0x1FFFFu);
                        unsigned u0 = hu16[(s0 << 5) + q];
                        unsigned u1 = hu16[(s1 << 5) + q];
                        ax[j] += blo(u0) + blo(u1);
                        ay[j] += bhi(u0) + bhi(u1);
                    }
                    for (; k + 2 <= b; k += 2) {
                        unsigned u = hu16[((sorted[k + half] & 0x1FFFFu) << 5) + q];
                        ax[j] += blo(u); ay[j] += bhi(u);
                    }
                    if (k < b && half == 0) {
                        unsigned u = hu16[((sorted[k] & 0x1FFFFu) << 5) + q];
                        ax[j] += blo(u); ay[j] += bhi(u);
                    }
                }
            } else {
#pragma unroll
                for (int j = 0; j < 8; j++) {
                    int il = wv + 8 * j;
                    int a = loc_l[il], b = loc_l[il + 1];
                    dg[j] += b - a;
                    int k = a;
                    for (; k + 2 <= b; k += 2) {
                        unsigned u = hu16[((stage[k + half] & 0x1FFFFu) << 5) + q];
                        ax[j] += blo(u); ay[j] += bhi(u);
                    }
                    if (k < b && half == 0) {
                        unsigned u = hu16[((stage[k] & 0x1FFFFu) << 5) + q];
                        ax[j] += blo(u); ay[j] += bhi(u);
                    }
                }
            }
        } else {
            // overflow fallback: filter-scan unsorted cell
            int cbeg = binoff[c], cend = binoff[c + 1];
#pragma unroll
            for (int j = 0; j < 8; j++) {
                int il = wv + 8 * j;
                unsigned want = ((unsigned)g << 6) | (unsigned)il;
                for (int k = cbeg; k < cend; k++) {
                    unsigned e = stage[k];
                    if (((e >> 17) & 511u) == want) {
                        dg[j]++;
                        if (half == 0) {
                            unsigned u = hu16[((e & 0x1FFFFu) << 5) + q];
                            ax[j] += blo(u); ay[j] += bhi(u);
                        }
                    }
                }
            }
        }
        __syncthreads();
    }

    float m = stats[0], ssum = stats[1];
    const float2* PF2 = (const float2*)pf;
#pragma unroll
    for (int j = 0; j < 8; j++) {
        int il = wv + 8 * j;
        int i = r * 64 + il;
        if (i >= N_ITEMS) continue;
        ax[j] += __shfl_xor(ax[j], 32);
        ay[j] += __shfl_xor(ay[j], 32);
        if (half == 0) {
            float deg = (float)dg[j];
            if (deg < 1.f) deg = 1.f;
            float sc = expf(edge_w[i] - m) / (ssum * deg);
            float2 pv = PF2[(size_t)i * 32 + q];
            float vx = (ax[j] + 0.5f * tanhf(pv.x)) * sc;
            float vy = (ay[j] + 0.5f * tanhf(pv.y)) * sc;
            rst16[(size_t)i * 32 + q] = bpack(vx, vy);
        }
    }
}

// ---------------------------------------------------------------------------
__global__ __launch_bounds__(512) void pass2_bwd_kernel(
    const unsigned* __restrict__ rst16, const unsigned* __restrict__ stage,
    const int* __restrict__ binoff, const int* __restrict__ itemoff,
    float* __restrict__ out) {
    __shared__ int loc_l[65];
    __shared__ unsigned sorted[CAPP];
    int r = blockIdx.x;
    int B = r >> 3, g = r & 7;
    int tid = threadIdx.x, lane = tid & 63, wv = tid >> 6;
    int q = lane & 31, half = lane >> 5;

    float ax[8], ay[8];
    int dg[8];
#pragma unroll
    for (int j = 0; j < 8; j++) { ax[j] = 0.f; ay[j] = 0.f; dg[j] = 0; }

    for (int seg = 0; seg < BSEG; seg++) {
        int c = FB2 + B * BSEG + seg;
        if (tid <= 64) {
            int dl = g * 64 + tid;
            loc_l[tid] = (dl == 512) ? binoff[c + 1] : itemoff[(size_t)c * 512 + dl];
        }
        __syncthreads();
        if (loc_l[0] >= 0) {
            int loc0 = loc_l[0];
            int n = loc_l[64] - loc0;
            if (n <= CAPP) {
                for (int k = tid; k < n; k += 512) sorted[k] = stage[loc0 + k];
                __syncthreads();
#pragma unroll
                for (int j = 0; j < 8; j++) {
                    int il = wv + 8 * j;
                    int a = loc_l[il] - loc0, b = loc_l[il + 1] - loc0;
                    dg[j] += b - a;
                    int k = a;
                    for (; k + 4 <= b; k += 4) {
                        int d0 = (int)(sorted[k + half] & 0xFFFFu);
                        int d1 = (int)(sorted[k + 2 + half] & 0xFFFFu);
                        unsigned u0 = rst16[(d0 << 5) + q];
                        unsigned u1 = rst16[(d1 << 5) + q];
                        ax[j] += blo(u0) + blo(u1);
                        ay[j] += bhi(u0) + bhi(u1);
                    }
                    for (; k + 2 <= b; k += 2) {
                        unsigned u = rst16[((sorted[k + half] & 0xFFFFu) << 5) + q];
                        ax[j] += blo(u); ay[j] += bhi(u);
                    }
                    if (k < b && half == 0) {
                        unsigned u = rst16[((sorted[k] & 0xFFFFu) << 5) + q];
                        ax[j] += blo(u); ay[j] += bhi(u);
                    }
                }
            } else {
#pragma unroll
                for (int j = 0; j < 8; j++) {
                    int il = wv + 8 * j;
                    int a = loc_l[il], b = loc_l[il + 1];
                    dg[j] += b - a;
                    int k = a;
                    for (; k + 2 <= b; k += 2) {
                        unsigned u = rst16[((stage[k + half] & 0xFFFFu) << 5) + q];
                        ax[j] += blo(u); ay[j] += bhi(u);
                    }
                    if (k < b && half == 0) {
                        unsigned u = rst16[((stage[k] & 0xFFFFu) << 5) + q];
                        ax[j] += blo(u); ay[j] += bhi(u);
                    }
                }
            }
        } else {
            int cbeg = binoff[c], cend = binoff[c + 1];
#pragma unroll
            for (int j = 0; j < 8; j++) {
                int il = wv + 8 * j;
                unsigned want = ((unsigned)g << 6) | (unsigned)il;
                for (int k = cbeg; k < cend; k++) {
                    unsigned e = stage[k];
                    if (((e >> 16) & 511u) == want) {
                        dg[j]++;
                        if (half == 0) {
                            unsigned u = rst16[((e & 0xFFFFu) << 5) + q];
                            ax[j] += blo(u); ay[j] += bhi(u);
                        }
                    }
                }
            }
        }
        __syncthreads();
    }

    float2* OUT2 = (float2*)out;
#pragma unroll
    for (int j = 0; j < 8; j++) {
        int il = wv + 8 * j;
        int u = r * 64 + il;
        if (u >= N_USERS) continue;
        ax[j] += __shfl_xor(ax[j], 32);
        ay[j] += __shfl_xor(ay[j], 32);
        if (half == 0) {
            float deg = (float)dg[j];
            if (deg < 1.f) deg = 1.f;
            OUT2[(size_t)u * 32 + q] = make_float2(ax[j] / deg, ay[j] / deg);
        }
    }
}

// ---------------------------------------------------------------------------
extern "C" void kernel_launch(void* const* d_in, const int* in_sizes, int n_in,
                              void* d_out, int out_size, void* d_ws, size_t ws_size,
                              hipStream_t stream) {
    const float* h_user = (const float*)d_in[0];   // [N_USERS, D]
    const float* pf     = (const float*)d_in[1];   // [N_ITEMS, D]
    const float* edge_w = (const float*)d_in[2];   // [N_ITEMS]
    const int*   src    = (const int*)d_in[3];     // [N_EDGES]
    const int*   dst    = (const int*)d_in[4];     // [N_EDGES]
    float* out = (float*)d_out;                    // [N_USERS, D]

    // workspace carve-up (~38.5 MB)
    char* p = (char*)d_ws;
    int* gh      = (int*)p;     p += sizeof(int) * NB2;
    int* binoff  = (int*)p;     p += sizeof(int) * (NB2 + 1);
    int* gcur    = (int*)p;     p += sizeof(int) * NB2;
    unsigned* stage = (unsigned*)p; p += sizeof(unsigned) * (size_t)2 * N_EDGES;
    int* itemoff = (int*)p;     p += sizeof(int) * (size_t)NB2 * 512;
    unsigned* hu16  = (unsigned*)p; p += sizeof(unsigned) * (size_t)N_USERS * 32;
    unsigned* rst16 = (unsigned*)p; p += sizeof(unsigned) * (size_t)N_ITEMS * 32;
    float* stats = (float*)p;   p += 2 * sizeof(float);

    hipMemsetAsync(gh, 0, sizeof(int) * NB2, stream);

    hist_kernel<<<256, 256, 0, stream>>>(src, dst, gh);
    scan_excl<<<1, 1024, 0, stream>>>(gh, binoff, gcur, NB2);
    binfill_kernel<<<NCHUNK, 256, 0, stream>>>(src, dst, gcur, stage);
    refine_kernel<<<NB2, 512, 0, stream>>>(stage, binoff, itemoff);
    h2b_kernel<<<1024, 256, 0, stream>>>((const float2*)h_user, hu16, N_USERS * 32);
    softmax_stats_kernel<<<1, 1024, 0, stream>>>(edge_w, stats);
    pass2_fwd_kernel<<<FWD_WGS, 512, 0, stream>>>(hu16, pf, edge_w, stage, binoff, itemoff, stats, rst16);
    pass2_bwd_kernel<<<BWD_WGS, 512, 0, stream>>>(rst16, stage, binoff, itemoff, out);
}

// Round 10
// 407.388 us; speedup vs baseline: 1.0161x; 1.0161x over previous
//
#include <hip/hip_runtime.h>
#include <hip/hip_bf16.h>
#include <math.h>

#define N_USERS 100000
#define N_ITEMS 50000
#define N_EDGES 2000000
#define D 64

// Segment-keyed coarse bins: fwd bin = (d>>9)*8 + (s>>14), bwd = (s>>9)*4 + (d>>14)
#define SEG_SH 14
#define FSEG 8
#define BSEG 4
#define FB2 (98 * FSEG)              // 784
#define BB2 (196 * BSEG)             // 784
#define NB2 (FB2 + BB2)              // 1568
#define CHUNK 16384
#define NCHUNK ((N_EDGES + CHUNK - 1) / CHUNK)   // 123
#define FWD_WGS 782
#define BWD_WGS 1563
#define CAPR 4096                    // refine in-LDS cell capacity (mean 2551, sd ~50)
#define CAPT 4096                    // pass2 total per-WG edge capacity (fwd mean 2560)

// ---- bf16 pack/unpack helpers --------------------------------------------
__device__ __forceinline__ float blo(unsigned u) {
    union { unsigned i; float f; } c; c.i = u << 16; return c.f;
}
__device__ __forceinline__ float bhi(unsigned u) {
    union { unsigned i; float f; } c; c.i = u & 0xFFFF0000u; return c.f;
}
__device__ __forceinline__ unsigned bpack(float x, float y) {
    __hip_bfloat16 a = __float2bfloat16(x), b = __float2bfloat16(y);
    unsigned short ua = *reinterpret_cast<unsigned short*>(&a);
    unsigned short ub = *reinterpret_cast<unsigned short*>(&b);
    return (unsigned)ua | ((unsigned)ub << 16);
}

// ---------------------------------------------------------------------------
__global__ __launch_bounds__(256) void h2b_kernel(
    const float2* __restrict__ in, unsigned* __restrict__ out, int n) {
    int stride = gridDim.x * blockDim.x;
    for (int i = blockIdx.x * blockDim.x + threadIdx.x; i < n; i += stride) {
        float2 v = in[i];
        out[i] = bpack(v.x, v.y);
    }
}

// ---------------------------------------------------------------------------
__global__ __launch_bounds__(256) void hist_kernel(
    const int* __restrict__ src, const int* __restrict__ dst, int* __restrict__ gh) {
    __shared__ int h[NB2];
    for (int i = threadIdx.x; i < NB2; i += 256) h[i] = 0;
    __syncthreads();
    int stride = gridDim.x * blockDim.x;
    for (int e = blockIdx.x * blockDim.x + threadIdx.x; e < N_EDGES; e += stride) {
        int s = src[e], d = dst[e];
        atomicAdd(&h[(d >> 9) * FSEG + (s >> SEG_SH)], 1);
        atomicAdd(&h[FB2 + (s >> 9) * BSEG + (d >> SEG_SH)], 1);
    }
    __syncthreads();
    for (int i = threadIdx.x; i < NB2; i += 256) {
        int v = h[i];
        if (v) atomicAdd(&gh[i], v);
    }
}

// ---------------------------------------------------------------------------
__global__ void scan_excl(const int* __restrict__ in, int* __restrict__ out,
                          int* __restrict__ cur, int n) {
    const int T = 1024, E = 4;
    __shared__ int wsum[16];
    __shared__ int s_carry;
    if (threadIdx.x == 0) s_carry = 0;
    __syncthreads();

    int lane = threadIdx.x & 63;
    int wid  = threadIdx.x >> 6;

    for (int base = 0; base < n; base += T * E) {
        int idx0 = base + threadIdx.x * E;
        int v[E];
        int tot = 0;
#pragma unroll
        for (int e = 0; e < E; e++) {
            int i = idx0 + e;
            v[e] = (i < n) ? in[i] : 0;
            tot += v[e];
        }
        int incl = tot;
#pragma unroll
        for (int off = 1; off < 64; off <<= 1) {
            int t = __shfl_up(incl, off);
            if (lane >= off) incl += t;
        }
        if (lane == 63) wsum[wid] = incl;
        __syncthreads();
        if (wid == 0 && lane < 16) {
            int t = wsum[lane];
            int sc = t;
#pragma unroll
            for (int off = 1; off < 16; off <<= 1) {
                int u = __shfl_up(sc, off);
                if (lane >= off) sc += u;
            }
            wsum[lane] = sc - t;
        }
        __syncthreads();
        int wave_off = wsum[wid];
        int excl = s_carry + wave_off + incl - tot;
#pragma unroll
        for (int e = 0; e < E; e++) {
            int i = idx0 + e;
            if (i < n) { out[i] = excl; cur[i] = excl; }
            excl += v[e];
        }
        __syncthreads();
        if (threadIdx.x == T - 1) s_carry += wave_off + incl;
        __syncthreads();
    }
    if (threadIdx.x == 0) out[n] = s_carry;
}

// ---------------------------------------------------------------------------
// binfill: two-scan chunk-aggregated scatter over 1568 bins (runs ~21 entries).
// fwd entry: s(17b) | d_local9<<17 ; bwd entry: d(16b) | s_local9<<16.
// ---------------------------------------------------------------------------
__global__ __launch_bounds__(256) void binfill_kernel(
    const int* __restrict__ src, const int* __restrict__ dst,
    int* __restrict__ gcur, unsigned* __restrict__ stage) {
    __shared__ int cnt[NB2];
    __shared__ int gbase[NB2];
    __shared__ int lcur[NB2];
    int base = blockIdx.x * CHUNK;
    int nE = N_EDGES - base; if (nE > CHUNK) nE = CHUNK;

    for (int t = threadIdx.x; t < NB2; t += 256) { cnt[t] = 0; lcur[t] = 0; }
    __syncthreads();

    for (int k = threadIdx.x; k < nE; k += 256) {
        int s = src[base + k], d = dst[base + k];
        atomicAdd(&cnt[(d >> 9) * FSEG + (s >> SEG_SH)], 1);
        atomicAdd(&cnt[FB2 + (s >> 9) * BSEG + (d >> SEG_SH)], 1);
    }
    __syncthreads();
    for (int t = threadIdx.x; t < NB2; t += 256) {
        int cv = cnt[t];
        gbase[t] = cv ? atomicAdd(&gcur[t], cv) : 0;
    }
    __syncthreads();
    for (int k = threadIdx.x; k < nE; k += 256) {
        int s = src[base + k], d = dst[base + k];
        int bf = (d >> 9) * FSEG + (s >> SEG_SH);
        int p = atomicAdd(&lcur[bf], 1);
        stage[gbase[bf] + p] = (unsigned)s | ((unsigned)(d & 511) << 17);
        int bb = FB2 + (s >> 9) * BSEG + (d >> SEG_SH);
        int q2 = atomicAdd(&lcur[bb], 1);
        stage[gbase[bb] + q2] = (unsigned)d | ((unsigned)(s & 511) << 16);
    }
}

// ---------------------------------------------------------------------------
// refine: one 512-thread WG per cell. In-LDS counting-sort of the cell by its
// 9-bit local id (entries reordered, written back densely) and per-local-id
// offset table itemoff[c*512 + dl]. Overflow cells flagged -1.
// ---------------------------------------------------------------------------
__global__ __launch_bounds__(512) void refine_kernel(
    unsigned* __restrict__ stage, const int* __restrict__ binoff,
    int* __restrict__ itemoff) {
    __shared__ unsigned ebuf[CAPR];
    __shared__ unsigned sbuf[CAPR];
    __shared__ int cnt[512];
    __shared__ int loc[512];
    __shared__ int lcur[512];
    __shared__ int part[8];
    int c = blockIdx.x;
    int beg = binoff[c], end = binoff[c + 1];
    int n = end - beg;
    int tid = threadIdx.x, lane = tid & 63, wv = tid >> 6;
    int sh = (c < FB2) ? 17 : 16;

    if (n > CAPR) {   // statistically unreachable; flag for pass2 fallback
        itemoff[(size_t)c * 512 + tid] = -1;
        return;
    }

    cnt[tid] = 0; lcur[tid] = 0;
    for (int k = tid; k < n; k += 512) ebuf[k] = stage[beg + k];
    __syncthreads();
    for (int k = tid; k < n; k += 512)
        atomicAdd(&cnt[(ebuf[k] >> sh) & 511], 1);
    __syncthreads();
    {
        int v = cnt[tid];
        int incl = v;
#pragma unroll
        for (int off = 1; off < 64; off <<= 1) {
            int t = __shfl_up(incl, off);
            if (lane >= off) incl += t;
        }
        if (lane == 63) part[wv] = incl;
        __syncthreads();
        if (tid == 0) {
            int run = 0;
#pragma unroll
            for (int w = 0; w < 8; w++) { int t = part[w]; part[w] = run; run += t; }
        }
        __syncthreads();
        loc[tid] = incl - v + part[wv];
    }
    __syncthreads();
    for (int k = tid; k < n; k += 512) {
        unsigned e = ebuf[k];
        int dl = (e >> sh) & 511;
        int p = atomicAdd(&lcur[dl], 1);
        sbuf[loc[dl] + p] = e;
    }
    __syncthreads();
    for (int k = tid; k < n; k += 512) stage[beg + k] = sbuf[k];
    itemoff[(size_t)c * 512 + tid] = beg + loc[tid];
}

// ---------------------------------------------------------------------------
__global__ void softmax_stats_kernel(const float* __restrict__ w, float* __restrict__ stats) {
    __shared__ float red[16];
    int tid = threadIdx.x, lane = tid & 63, wid = tid >> 6;

    float m = -INFINITY;
    for (int i = tid; i < N_ITEMS; i += 1024) m = fmaxf(m, w[i]);
#pragma unroll
    for (int off = 32; off; off >>= 1) m = fmaxf(m, __shfl_xor(m, off));
    if (lane == 0) red[wid] = m;
    __syncthreads();
    if (tid == 0) {
        float t = red[0];
        for (int k = 1; k < 16; k++) t = fmaxf(t, red[k]);
        red[0] = t;
    }
    __syncthreads();
    m = red[0];
    __syncthreads();

    float s = 0.f;
    for (int i = tid; i < N_ITEMS; i += 1024) s += expf(w[i] - m);
#pragma unroll
    for (int off = 32; off; off >>= 1) s += __shfl_xor(s, off);
    if (lane == 0) red[wid] = s;
    __syncthreads();
    if (tid == 0) {
        float t = 0.f;
        for (int k = 0; k < 16; k++) t += red[k];
        stats[0] = m;
        stats[1] = t;
    }
}

// ---------------------------------------------------------------------------
// pass2 fwd: one 512-thread WG per 64 items. TWO barriers total:
// (1) load FSEG x 65 group bounds into LDS; (2) copy all contiguous segment
// runs (~2560 entries) into one LDS buffer. Then the full gather runs
// BARRIER-FREE: LDS broadcast edge ids + hu16 gathers, per-item VGPR acc.
// ---------------------------------------------------------------------------
__global__ __launch_bounds__(512) void pass2_fwd_kernel(
    const unsigned* __restrict__ hu16, const float* __restrict__ pf,
    const float* __restrict__ edge_w, const unsigned* __restrict__ stage,
    const int* __restrict__ binoff, const int* __restrict__ itemoff,
    const float* __restrict__ stats, unsigned* __restrict__ rst16) {
    __shared__ int bnd[FSEG][65];
    __shared__ unsigned sorted[CAPT];
    int r = blockIdx.x;
    int B = r >> 3, g = r & 7;
    int tid = threadIdx.x, lane = tid & 63, wv = tid >> 6;
    int q = lane & 31, half = lane >> 5;

    for (int t = tid; t < FSEG * 65; t += 512) {
        int seg = t / 65, o = t - seg * 65;
        int c = B * FSEG + seg;
        int dl = g * 64 + o;
        bnd[seg][o] = (dl == 512) ? binoff[c + 1] : itemoff[(size_t)c * 512 + dl];
    }
    __syncthreads();

    // per-thread identical: LDS layout of the segment runs
    int soff[FSEG + 1];
    bool uselds[FSEG];
    soff[0] = 0;
#pragma unroll
    for (int seg = 0; seg < FSEG; seg++) {
        int c0 = bnd[seg][0];
        int n = (c0 >= 0) ? (bnd[seg][64] - c0) : 0;
        if (c0 >= 0 && soff[seg] + n <= CAPT) { uselds[seg] = true;  soff[seg + 1] = soff[seg] + n; }
        else                                  { uselds[seg] = false; soff[seg + 1] = soff[seg]; }
    }
#pragma unroll
    for (int seg = 0; seg < FSEG; seg++) {
        if (!uselds[seg]) continue;
        int c0 = bnd[seg][0], n = soff[seg + 1] - soff[seg];
        for (int k = tid; k < n; k += 512) sorted[soff[seg] + k] = stage[c0 + k];
    }
    __syncthreads();

    float ax[8], ay[8];
    int dg[8];
#pragma unroll
    for (int j = 0; j < 8; j++) { ax[j] = 0.f; ay[j] = 0.f; dg[j] = 0; }

    for (int seg = 0; seg < FSEG; seg++) {
        int c0 = bnd[seg][0];
        if (c0 >= 0) {
            if (uselds[seg]) {
                int rel = soff[seg] - c0;
#pragma unroll
                for (int j = 0; j < 8; j++) {
                    int il = wv + 8 * j;
                    int a = bnd[seg][il], b = bnd[seg][il + 1];
                    dg[j] += b - a;
                    int k = a;
                    for (; k + 4 <= b; k += 4) {
                        int s0 = (int)(sorted[rel + k + half] & 0x1FFFFu);
                        int s1 = (int)(sorted[rel + k + 2 + half] & 0x1FFFFu);
                        unsigned u0 = hu16[(s0 << 5) + q];
                        unsigned u1 = hu16[(s1 << 5) + q];
                        ax[j] += blo(u0) + blo(u1);
                        ay[j] += bhi(u0) + bhi(u1);
                    }
                    for (; k + 2 <= b; k += 2) {
                        unsigned u = hu16[((sorted[rel + k + half] & 0x1FFFFu) << 5) + q];
                        ax[j] += blo(u); ay[j] += bhi(u);
                    }
                    if (k < b && half == 0) {
                        unsigned u = hu16[((sorted[rel + k] & 0x1FFFFu) << 5) + q];
                        ax[j] += blo(u); ay[j] += bhi(u);
                    }
                }
            } else {
#pragma unroll
                for (int j = 0; j < 8; j++) {
                    int il = wv + 8 * j;
                    int a = bnd[seg][il], b = bnd[seg][il + 1];
                    dg[j] += b - a;
                    int k = a;
                    for (; k + 2 <= b; k += 2) {
                        unsigned u = hu16[((stage[k + half] & 0x1FFFFu) << 5) + q];
                        ax[j] += blo(u); ay[j] += bhi(u);
                    }
                    if (k < b && half == 0) {
                        unsigned u = hu16[((stage[k] & 0x1FFFFu) << 5) + q];
                        ax[j] += blo(u); ay[j] += bhi(u);
                    }
                }
            }
        } else {
            // overflow fallback: filter-scan unsorted cell from global
            int c = B * FSEG + seg;
            int cbeg = binoff[c], cend = binoff[c + 1];
#pragma unroll
            for (int j = 0; j < 8; j++) {
                int il = wv + 8 * j;
                unsigned want = ((unsigned)g << 6) | (unsigned)il;
                for (int k = cbeg; k < cend; k++) {
                    unsigned e = stage[k];
                    if (((e >> 17) & 511u) == want) {
                        dg[j]++;
                        if (half == 0) {
                            unsigned u = hu16[((e & 0x1FFFFu) << 5) + q];
                            ax[j] += blo(u); ay[j] += bhi(u);
                        }
                    }
                }
            }
        }
    }

    float m = stats[0], ssum = stats[1];
    const float2* PF2 = (const float2*)pf;
#pragma unroll
    for (int j = 0; j < 8; j++) {
        int il = wv + 8 * j;
        int i = r * 64 + il;
        if (i >= N_ITEMS) continue;
        ax[j] += __shfl_xor(ax[j], 32);
        ay[j] += __shfl_xor(ay[j], 32);
        if (half == 0) {
            float deg = (float)dg[j];
            if (deg < 1.f) deg = 1.f;
            float sc = expf(edge_w[i] - m) / (ssum * deg);
            float2 pv = PF2[(size_t)i * 32 + q];
            float vx = (ax[j] + 0.5f * tanhf(pv.x)) * sc;
            float vy = (ay[j] + 0.5f * tanhf(pv.y)) * sc;
            rst16[(size_t)i * 32 + q] = bpack(vx, vy);
        }
    }
}

// ---------------------------------------------------------------------------
// pass2 bwd: same two-barrier plan over BSEG segments of rst16.
// ---------------------------------------------------------------------------
__global__ __launch_bounds__(512) void pass2_bwd_kernel(
    const unsigned* __restrict__ rst16, const unsigned* __restrict__ stage,
    const int* __restrict__ binoff, const int* __restrict__ itemoff,
    float* __restrict__ out) {
    __shared__ int bnd[BSEG][65];
    __shared__ unsigned sorted[CAPT];
    int r = blockIdx.x;
    int B = r >> 3, g = r & 7;
    int tid = threadIdx.x, lane = tid & 63, wv = tid >> 6;
    int q = lane & 31, half = lane >> 5;

    for (int t = tid; t < BSEG * 65; t += 512) {
        int seg = t / 65, o = t - seg * 65;
        int c = FB2 + B * BSEG + seg;
        int dl = g * 64 + o;
        bnd[seg][o] = (dl == 512) ? binoff[c + 1] : itemoff[(size_t)c * 512 + dl];
    }
    __syncthreads();

    int soff[BSEG + 1];
    bool uselds[BSEG];
    soff[0] = 0;
#pragma unroll
    for (int seg = 0; seg < BSEG; seg++) {
        int c0 = bnd[seg][0];
        int n = (c0 >= 0) ? (bnd[seg][64] - c0) : 0;
        if (c0 >= 0 && soff[seg] + n <= CAPT) { uselds[seg] = true;  soff[seg + 1] = soff[seg] + n; }
        else                                  { uselds[seg] = false; soff[seg + 1] = soff[seg]; }
    }
#pragma unroll
    for (int seg = 0; seg < BSEG; seg++) {
        if (!uselds[seg]) continue;
        int c0 = bnd[seg][0], n = soff[seg + 1] - soff[seg];
        for (int k = tid; k < n; k += 512) sorted[soff[seg] + k] = stage[c0 + k];
    }
    __syncthreads();

    float ax[8], ay[8];
    int dg[8];
#pragma unroll
    for (int j = 0; j < 8; j++) { ax[j] = 0.f; ay[j] = 0.f; dg[j] = 0; }

    for (int seg = 0; seg < BSEG; seg++) {
        int c0 = bnd[seg][0];
        if (c0 >= 0) {
            if (uselds[seg]) {
                int rel = soff[seg] - c0;
#pragma unroll
                for (int j = 0; j < 8; j++) {
                    int il = wv + 8 * j;
                    int a = bnd[seg][il], b = bnd[seg][il + 1];
                    dg[j] += b - a;
                    int k = a;
                    for (; k + 4 <= b; k += 4) {
                        int d0 = (int)(sorted[rel + k + half] & 0xFFFFu);
                        int d1 = (int)(sorted[rel + k + 2 + half] & 0xFFFFu);
                        unsigned u0 = rst16[(d0 << 5) + q];
                        unsigned u1 = rst16[(d1 << 5) + q];
                        ax[j] += blo(u0) + blo(u1);
                        ay[j] += bhi(u0) + bhi(u1);
                    }
                    for (; k + 2 <= b; k += 2) {
                        unsigned u = rst16[((sorted[rel + k + half] & 0xFFFFu) << 5) + q];
                        ax[j] += blo(u); ay[j] += bhi(u);
                    }
                    if (k < b && half == 0) {
                        unsigned u = rst16[((sorted[rel + k] & 0xFFFFu) << 5) + q];
                        ax[j] += blo(u); ay[j] += bhi(u);
                    }
                }
            } else {
#pragma unroll
                for (int j = 0; j < 8; j++) {
                    int il = wv + 8 * j;
                    int a = bnd[seg][il], b = bnd[seg][il + 1];
                    dg[j] += b - a;
                    int k = a;
                    for (; k + 2 <= b; k += 2) {
                        unsigned u = rst16[((stage[k + half] & 0xFFFFu) << 5) + q];
                        ax[j] += blo(u); ay[j] += bhi(u);
                    }
                    if (k < b && half == 0) {
                        unsigned u = rst16[((stage[k] & 0xFFFFu) << 5) + q];
                        ax[j] += blo(u); ay[j] += bhi(u);
                    }
                }
            }
        } else {
            int c = FB2 + B * BSEG + seg;
            int cbeg = binoff[c], cend = binoff[c + 1];
#pragma unroll
            for (int j = 0; j < 8; j++) {
                int il = wv + 8 * j;
                unsigned want = ((unsigned)g << 6) | (unsigned)il;
                for (int k = cbeg; k < cend; k++) {
                    unsigned e = stage[k];
                    if (((e >> 16) & 511u) == want) {
                        dg[j]++;
                        if (half == 0) {
                            unsigned u = rst16[((e & 0xFFFFu) << 5) + q];
                            ax[j] += blo(u); ay[j] += bhi(u);
                        }
                    }
                }
            }
        }
    }

    float2* OUT2 = (float2*)out;
#pragma unroll
    for (int j = 0; j < 8; j++) {
        int il = wv + 8 * j;
        int u = r * 64 + il;
        if (u >= N_USERS) continue;
        ax[j] += __shfl_xor(ax[j], 32);
        ay[j] += __shfl_xor(ay[j], 32);
        if (half == 0) {
            float deg = (float)dg[j];
            if (deg < 1.f) deg = 1.f;
            OUT2[(size_t)u * 32 + q] = make_float2(ax[j] / deg, ay[j] / deg);
        }
    }
}

// ---------------------------------------------------------------------------
extern "C" void kernel_launch(void* const* d_in, const int* in_sizes, int n_in,
                              void* d_out, int out_size, void* d_ws, size_t ws_size,
                              hipStream_t stream) {
    const float* h_user = (const float*)d_in[0];   // [N_USERS, D]
    const float* pf     = (const float*)d_in[1];   // [N_ITEMS, D]
    const float* edge_w = (const float*)d_in[2];   // [N_ITEMS]
    const int*   src    = (const int*)d_in[3];     // [N_EDGES]
    const int*   dst    = (const int*)d_in[4];     // [N_EDGES]
    float* out = (float*)d_out;                    // [N_USERS, D]

    // workspace carve-up (~38.5 MB)
    char* p = (char*)d_ws;
    int* gh      = (int*)p;     p += sizeof(int) * NB2;
    int* binoff  = (int*)p;     p += sizeof(int) * (NB2 + 1);
    int* gcur    = (int*)p;     p += sizeof(int) * NB2;
    unsigned* stage = (unsigned*)p; p += sizeof(unsigned) * (size_t)2 * N_EDGES;
    int* itemoff = (int*)p;     p += sizeof(int) * (size_t)NB2 * 512;
    unsigned* hu16  = (unsigned*)p; p += sizeof(unsigned) * (size_t)N_USERS * 32;
    unsigned* rst16 = (unsigned*)p; p += sizeof(unsigned) * (size_t)N_ITEMS * 32;
    float* stats = (float*)p;   p += 2 * sizeof(float);

    hipMemsetAsync(gh, 0, sizeof(int) * NB2, stream);

    hist_kernel<<<256, 256, 0, stream>>>(src, dst, gh);
    scan_excl<<<1, 1024, 0, stream>>>(gh, binoff, gcur, NB2);
    binfill_kernel<<<NCHUNK, 256, 0, stream>>>(src, dst, gcur, stage);
    refine_kernel<<<NB2, 512, 0, stream>>>(stage, binoff, itemoff);
    h2b_kernel<<<1024, 256, 0, stream>>>((const float2*)h_user, hu16, N_USERS * 32);
    softmax_stats_kernel<<<1, 1024, 0, stream>>>(edge_w, stats);
    pass2_fwd_kernel<<<FWD_WGS, 512, 0, stream>>>(hu16, pf, edge_w, stage, binoff, itemoff, stats, rst16);
    pass2_bwd_kernel<<<BWD_WGS, 512, 0, stream>>>(rst16, stage, binoff, itemoff, out);
}